// Round 1
// baseline (2869.778 us; speedup 1.0000x reference)
//
#include <hip/hip_runtime.h>

#define D 128
#define BM 64

// ---------------------------------------------------------------------------
// Kernel 1: edge scatter  h[row] += val * features[col]
// One edge is handled by 32 threads, each owning 4 consecutive floats (float4).
// 204.8M fp32 atomics via fire-and-forget global_atomic_add_f32.
// ---------------------------------------------------------------------------
__global__ __launch_bounds__(256) void edge_scatter_kernel(
    const float4* __restrict__ feat4,
    const int* __restrict__ rows,
    const int* __restrict__ cols,
    const float* __restrict__ vals,
    float* __restrict__ h,
    int E)
{
    int idx = blockIdx.x * 256 + threadIdx.x;   // E*32 = 51.2M fits int
    if (idx >= E * 32) return;
    int e = idx >> 5;
    int p = idx & 31;

    int r = rows[e];
    int c = cols[e];
    float v = vals[e];

    float4 f = feat4[c * 32 + p];
    float* hr = h + (long long)r * D + p * 4;
    unsafeAtomicAdd(hr + 0, v * f.x);
    unsafeAtomicAdd(hr + 1, v * f.y);
    unsafeAtomicAdd(hr + 2, v * f.z);
    unsafeAtomicAdd(hr + 3, v * f.w);
}

// ---------------------------------------------------------------------------
// Kernel 2: fused  out = leakyrelu((f+h)@W1 + (f*h)@W2 + b1 + b2)
// Block of 256 threads handles BM=64 nodes. A/M tiles staged in LDS (64 KB).
// Thread = (colgroup c: 4 cols via float4) x (nodegroup g: 8 nodes stride 8).
// Safe when h aliases out: each block stages its own rows into LDS before
// writing them, and blocks own disjoint row ranges.
// ---------------------------------------------------------------------------
__global__ __launch_bounds__(256) void fused_gemm_kernel(
    const float* __restrict__ feat,
    const float* __restrict__ h,
    const float* __restrict__ W1,
    const float* __restrict__ b1,
    const float* __restrict__ W2,
    const float* __restrict__ b2,
    float* __restrict__ out,
    int N)
{
    __shared__ float a_lds[BM][D];   // (f+h)[node][k]   32 KB
    __shared__ float m_lds[BM][D];   // (f*h)[node][k]   32 KB

    const int tid = threadIdx.x;
    const int block0 = blockIdx.x * BM;

    const float4* feat4 = (const float4*)feat;
    const float4* h4    = (const float4*)h;

    // --- stage 64 nodes x 128 cols of a and m into LDS ---
    #pragma unroll
    for (int it = 0; it < 8; ++it) {
        int idx  = tid + it * 256;        // 0..2047 = 64 nodes x 32 float4s
        int node = idx >> 5;
        int p    = idx & 31;
        int gnode = block0 + node;
        float4 fv = make_float4(0.f, 0.f, 0.f, 0.f);
        float4 hv = make_float4(0.f, 0.f, 0.f, 0.f);
        if (gnode < N) {
            fv = feat4[gnode * 32 + p];
            hv = h4[gnode * 32 + p];
        }
        float4 av = make_float4(fv.x + hv.x, fv.y + hv.y, fv.z + hv.z, fv.w + hv.w);
        float4 mv = make_float4(fv.x * hv.x, fv.y * hv.y, fv.z * hv.z, fv.w * hv.w);
        *(float4*)&a_lds[node][p * 4] = av;
        *(float4*)&m_lds[node][p * 4] = mv;
    }
    __syncthreads();

    const int c = tid & 31;   // column group -> cols 4c..4c+3
    const int g = tid >> 5;   // node offset  -> nodes g, g+8, ..., g+56

    float acc[8][4] = {};

    const float4* W1v = (const float4*)W1;
    const float4* W2v = (const float4*)W2;

    for (int k = 0; k < D; ++k) {
        float4 w1 = W1v[k * 32 + c];
        float4 w2 = W2v[k * 32 + c];
        #pragma unroll
        for (int t = 0; t < 8; ++t) {
            float av = a_lds[g + 8 * t][k];
            float mv = m_lds[g + 8 * t][k];
            acc[t][0] = fmaf(av, w1.x, fmaf(mv, w2.x, acc[t][0]));
            acc[t][1] = fmaf(av, w1.y, fmaf(mv, w2.y, acc[t][1]));
            acc[t][2] = fmaf(av, w1.z, fmaf(mv, w2.z, acc[t][2]));
            acc[t][3] = fmaf(av, w1.w, fmaf(mv, w2.w, acc[t][3]));
        }
    }

    float4 bb1 = ((const float4*)b1)[c];
    float4 bb2 = ((const float4*)b2)[c];
    const float bx = bb1.x + bb2.x;
    const float by = bb1.y + bb2.y;
    const float bz = bb1.z + bb2.z;
    const float bw = bb1.w + bb2.w;

    #pragma unroll
    for (int t = 0; t < 8; ++t) {
        int gnode = block0 + g + 8 * t;
        if (gnode >= N) continue;
        float4 o;
        o.x = acc[t][0] + bx;
        o.y = acc[t][1] + by;
        o.z = acc[t][2] + bz;
        o.w = acc[t][3] + bw;
        o.x = (o.x >= 0.f) ? o.x : 0.01f * o.x;
        o.y = (o.y >= 0.f) ? o.y : 0.01f * o.y;
        o.z = (o.z >= 0.f) ? o.z : 0.01f * o.z;
        o.w = (o.w >= 0.f) ? o.w : 0.01f * o.w;
        ((float4*)out)[gnode * 32 + c] = o;
    }
}

extern "C" void kernel_launch(void* const* d_in, const int* in_sizes, int n_in,
                              void* d_out, int out_size, void* d_ws, size_t ws_size,
                              hipStream_t stream) {
    const float* feat = (const float*)d_in[0];
    const int*   rows = (const int*)d_in[1];
    const int*   cols = (const int*)d_in[2];
    const float* vals = (const float*)d_in[3];
    const float* W1   = (const float*)d_in[4];
    const float* b1   = (const float*)d_in[5];
    const float* W2   = (const float*)d_in[6];
    const float* b2   = (const float*)d_in[7];

    const int N = in_sizes[0] / D;
    const int E = in_sizes[1];
    float* out = (float*)d_out;

    // h_neigh buffer: prefer workspace, else fall back to d_out (safe: GEMM
    // stages each block's h rows into LDS before overwriting them).
    size_t hbytes = (size_t)N * D * sizeof(float);
    float* h = (ws_size >= hbytes) ? (float*)d_ws : out;

    hipMemsetAsync(h, 0, hbytes, stream);

    int scatter_items = E * 32;
    edge_scatter_kernel<<<(scatter_items + 255) / 256, 256, 0, stream>>>(
        (const float4*)feat, rows, cols, vals, h, E);

    fused_gemm_kernel<<<(N + BM - 1) / BM, 256, 0, stream>>>(
        feat, h, W1, b1, W2, b2, out, N);
}

// Round 2
// 591.688 us; speedup vs baseline: 4.8502x; 4.8502x over previous
//
#include <hip/hip_runtime.h>

#define D 128
#define BM 64

// ===========================================================================
// Sorted (CSR) path: hist -> scan -> scatter_sort -> gather spmm.
// Eliminates the 3.2 GB of HBM atomic-RMW traffic the naive scatter caused.
// ===========================================================================

__global__ __launch_bounds__(256) void hist_kernel(
    const int* __restrict__ rows, int* __restrict__ counts, int E)
{
    int e = blockIdx.x * 256 + threadIdx.x;
    if (e < E) atomicAdd(&counts[rows[e]], 1);
}

// Exclusive scan of counts[0..N) -> row_start[0..N]; also copies to cursor.
// Single persistent block of 1024 threads; wave-shuffle scan per 1024-chunk.
// counts may alias row_start (in-place): each index touched by one thread,
// read-before-write within that thread.
__global__ __launch_bounds__(1024) void scan_kernel(
    const int* __restrict__ counts, int* __restrict__ row_start,
    int* __restrict__ cursor, int N)
{
    __shared__ int wsum[16];
    __shared__ int carry_s;
    const int tid  = threadIdx.x;
    const int lane = tid & 63;
    const int wid  = tid >> 6;

    if (tid == 0) carry_s = 0;
    __syncthreads();

    for (int base = 0; base < N; base += 1024) {
        int i = base + tid;
        int x = (i < N) ? counts[i] : 0;
        int c0 = carry_s;

        // inclusive scan within wave (64 lanes)
        int v = x;
        #pragma unroll
        for (int off = 1; off < 64; off <<= 1) {
            int y = __shfl_up(v, off, 64);
            if (lane >= off) v += y;
        }
        if (lane == 63) wsum[wid] = v;
        __syncthreads();
        if (wid == 0 && lane < 16) {
            int s = wsum[lane];
            #pragma unroll
            for (int off = 1; off < 16; off <<= 1) {
                int y = __shfl_up(s, off, 64);
                if (lane >= off) s += y;
            }
            wsum[lane] = s;   // inclusive wave-sums
        }
        __syncthreads();

        int wave_excl = wid ? wsum[wid - 1] : 0;
        int excl = wave_excl + v - x;
        int total = wsum[15];
        if (i < N) {
            int val = c0 + excl;
            row_start[i] = val;
            cursor[i]    = val;
        }
        __syncthreads();                    // all reads of wsum/carry_s done
        if (tid == 0) carry_s = c0 + total;
        __syncthreads();                    // carry visible; wsum reusable
    }
    if (tid == 0) row_start[N] = carry_s;   // == E
}

__global__ __launch_bounds__(256) void scatter_sort_kernel(
    const int* __restrict__ rows, const int* __restrict__ cols,
    const float* __restrict__ vals, int* __restrict__ cursor,
    int* __restrict__ scols, float* __restrict__ svals, int E)
{
    int e = blockIdx.x * 256 + threadIdx.x;
    if (e < E) {
        int r = rows[e];
        int p = atomicAdd(&cursor[r], 1);
        scols[p] = cols[e];
        svals[p] = vals[e];
    }
}

// One wave per row: 64 lanes x float2 hold the 128-float accumulator.
// Per edge: wave-uniform (col,val) broadcast + one coalesced 512B gather.
__global__ __launch_bounds__(256) void spmm_kernel(
    const float2* __restrict__ feat2,
    const int* __restrict__ row_start,
    const int* __restrict__ scols,
    const float* __restrict__ svals,
    float2* __restrict__ h2, int N)
{
    int gw = (blockIdx.x * 256 + threadIdx.x) >> 6;   // global wave = row
    int lane = threadIdx.x & 63;
    if (gw >= N) return;

    int s = row_start[gw];
    int e = row_start[gw + 1];

    float2 acc = make_float2(0.f, 0.f);
    int j = s;
    for (; j + 1 < e; j += 2) {
        int   c0 = scols[j],     c1 = scols[j + 1];
        float v0 = svals[j],     v1 = svals[j + 1];
        float2 f0 = feat2[(size_t)c0 * 64 + lane];
        float2 f1 = feat2[(size_t)c1 * 64 + lane];
        acc.x = fmaf(v0, f0.x, acc.x);
        acc.y = fmaf(v0, f0.y, acc.y);
        acc.x = fmaf(v1, f1.x, acc.x);
        acc.y = fmaf(v1, f1.y, acc.y);
    }
    if (j < e) {
        int   c = scols[j];
        float v = svals[j];
        float2 f = feat2[(size_t)c * 64 + lane];
        acc.x = fmaf(v, f.x, acc.x);
        acc.y = fmaf(v, f.y, acc.y);
    }
    h2[(size_t)gw * 64 + lane] = acc;
}

// ===========================================================================
// Fallback: original fire-and-forget atomic scatter (used only if ws_size
// can't hold the CSR scratch).
// ===========================================================================
__global__ __launch_bounds__(256) void edge_scatter_kernel(
    const float4* __restrict__ feat4,
    const int* __restrict__ rows,
    const int* __restrict__ cols,
    const float* __restrict__ vals,
    float* __restrict__ h,
    int E)
{
    int idx = blockIdx.x * 256 + threadIdx.x;
    if (idx >= E * 32) return;
    int e = idx >> 5;
    int p = idx & 31;
    int r = rows[e];
    int c = cols[e];
    float v = vals[e];
    float4 f = feat4[c * 32 + p];
    float* hr = h + (long long)r * D + p * 4;
    unsafeAtomicAdd(hr + 0, v * f.x);
    unsafeAtomicAdd(hr + 1, v * f.y);
    unsafeAtomicAdd(hr + 2, v * f.z);
    unsafeAtomicAdd(hr + 3, v * f.w);
}

// ===========================================================================
// Fused GEMM: out = leakyrelu((f+h)@W1 + (f*h)@W2 + b1 + b2)
// 256 threads / 64 nodes; a,m tiles staged in 64KB LDS.
// ===========================================================================
__global__ __launch_bounds__(256) void fused_gemm_kernel(
    const float* __restrict__ feat,
    const float* __restrict__ h,
    const float* __restrict__ W1,
    const float* __restrict__ b1,
    const float* __restrict__ W2,
    const float* __restrict__ b2,
    float* __restrict__ out,
    int N)
{
    __shared__ float a_lds[BM][D];
    __shared__ float m_lds[BM][D];

    const int tid = threadIdx.x;
    const int block0 = blockIdx.x * BM;

    const float4* feat4 = (const float4*)feat;
    const float4* h4    = (const float4*)h;

    #pragma unroll
    for (int it = 0; it < 8; ++it) {
        int idx  = tid + it * 256;
        int node = idx >> 5;
        int p    = idx & 31;
        int gnode = block0 + node;
        float4 fv = make_float4(0.f, 0.f, 0.f, 0.f);
        float4 hv = make_float4(0.f, 0.f, 0.f, 0.f);
        if (gnode < N) {
            fv = feat4[gnode * 32 + p];
            hv = h4[gnode * 32 + p];
        }
        float4 av = make_float4(fv.x + hv.x, fv.y + hv.y, fv.z + hv.z, fv.w + hv.w);
        float4 mv = make_float4(fv.x * hv.x, fv.y * hv.y, fv.z * hv.z, fv.w * hv.w);
        *(float4*)&a_lds[node][p * 4] = av;
        *(float4*)&m_lds[node][p * 4] = mv;
    }
    __syncthreads();

    const int c = tid & 31;
    const int g = tid >> 5;

    float acc[8][4] = {};

    const float4* W1v = (const float4*)W1;
    const float4* W2v = (const float4*)W2;

    for (int k = 0; k < D; ++k) {
        float4 w1 = W1v[k * 32 + c];
        float4 w2 = W2v[k * 32 + c];
        #pragma unroll
        for (int t = 0; t < 8; ++t) {
            float av = a_lds[g + 8 * t][k];
            float mv = m_lds[g + 8 * t][k];
            acc[t][0] = fmaf(av, w1.x, fmaf(mv, w2.x, acc[t][0]));
            acc[t][1] = fmaf(av, w1.y, fmaf(mv, w2.y, acc[t][1]));
            acc[t][2] = fmaf(av, w1.z, fmaf(mv, w2.z, acc[t][2]));
            acc[t][3] = fmaf(av, w1.w, fmaf(mv, w2.w, acc[t][3]));
        }
    }

    float4 bb1 = ((const float4*)b1)[c];
    float4 bb2 = ((const float4*)b2)[c];
    const float bx = bb1.x + bb2.x;
    const float by = bb1.y + bb2.y;
    const float bz = bb1.z + bb2.z;
    const float bw = bb1.w + bb2.w;

    #pragma unroll
    for (int t = 0; t < 8; ++t) {
        int gnode = block0 + g + 8 * t;
        if (gnode >= N) continue;
        float4 o;
        o.x = acc[t][0] + bx;
        o.y = acc[t][1] + by;
        o.z = acc[t][2] + bz;
        o.w = acc[t][3] + bw;
        o.x = (o.x >= 0.f) ? o.x : 0.01f * o.x;
        o.y = (o.y >= 0.f) ? o.y : 0.01f * o.y;
        o.z = (o.z >= 0.f) ? o.z : 0.01f * o.z;
        o.w = (o.w >= 0.f) ? o.w : 0.01f * o.w;
        ((float4*)out)[gnode * 32 + c] = o;
    }
}

extern "C" void kernel_launch(void* const* d_in, const int* in_sizes, int n_in,
                              void* d_out, int out_size, void* d_ws, size_t ws_size,
                              hipStream_t stream) {
    const float* feat = (const float*)d_in[0];
    const int*   rows = (const int*)d_in[1];
    const int*   cols = (const int*)d_in[2];
    const float* vals = (const float*)d_in[3];
    const float* W1   = (const float*)d_in[4];
    const float* b1   = (const float*)d_in[5];
    const float* W2   = (const float*)d_in[6];
    const float* b2   = (const float*)d_in[7];

    const int N = in_sizes[0] / D;
    const int E = in_sizes[1];
    float* out = (float*)d_out;

    // Workspace layout for the CSR path:
    //   h[N*128] f32 | row_start[N+1] i32 | cursor[N] i32 | scols[E] i32 | svals[E] f32
    size_t hbytes  = (size_t)N * D * sizeof(float);
    size_t need    = hbytes + ((size_t)(N + 1) + N + E + E) * 4;

    if (ws_size >= need) {
        float* h         = (float*)d_ws;
        int*   row_start = (int*)(h + (size_t)N * D);
        int*   cursor    = row_start + (N + 1);
        int*   scols     = cursor + N;
        float* svals     = (float*)(scols + E);

        // counts alias row_start[0..N)
        hipMemsetAsync(row_start, 0, (size_t)(N + 1) * sizeof(int), stream);
        hist_kernel<<<(E + 255) / 256, 256, 0, stream>>>(rows, row_start, E);
        scan_kernel<<<1, 1024, 0, stream>>>(row_start, row_start, cursor, N);
        scatter_sort_kernel<<<(E + 255) / 256, 256, 0, stream>>>(
            rows, cols, vals, cursor, scols, svals, E);

        int spmm_blocks = (N * 64 + 255) / 256;   // one wave per row
        spmm_kernel<<<spmm_blocks, 256, 0, stream>>>(
            (const float2*)feat, row_start, scols, svals, (float2*)h, N);

        fused_gemm_kernel<<<(N + BM - 1) / BM, 256, 0, stream>>>(
            feat, h, W1, b1, W2, b2, out, N);
    } else {
        // Fallback: atomic scatter path
        float* h = (ws_size >= hbytes) ? (float*)d_ws : out;
        hipMemsetAsync(h, 0, hbytes, stream);
        int scatter_items = E * 32;
        edge_scatter_kernel<<<(scatter_items + 255) / 256, 256, 0, stream>>>(
            (const float4*)feat, rows, cols, vals, h, E);
        fused_gemm_kernel<<<(N + BM - 1) / BM, 256, 0, stream>>>(
            feat, h, W1, b1, W2, b2, out, N);
    }
}

// Round 3
// 373.775 us; speedup vs baseline: 7.6778x; 1.5830x over previous
//
#include <hip/hip_runtime.h>

#define D 128
#define BM 64

typedef short short8 __attribute__((ext_vector_type(8)));
typedef float f32x4 __attribute__((ext_vector_type(4)));

__device__ __forceinline__ unsigned short f2bf(float x) {
    unsigned u = __float_as_uint(x);
    unsigned r = (u + 0x7fffu + ((u >> 16) & 1u)) >> 16;   // RNE
    return (unsigned short)r;
}

// ===========================================================================
// CSR build: hist -> hierarchical scan (3 kernels) -> scatter_sort (packed)
// ===========================================================================

__global__ __launch_bounds__(256) void hist_kernel(
    const int* __restrict__ rows, int* __restrict__ counts, int E)
{
    int e = blockIdx.x * 256 + threadIdx.x;
    if (e < E) atomicAdd(&counts[rows[e]], 1);
}

// pass1: per-1024-chunk totals
__global__ __launch_bounds__(256) void scan_pass1(
    const int* __restrict__ counts, int* __restrict__ btot, int N)
{
    int tid = threadIdx.x;
    int i = blockIdx.x * 1024 + tid * 4;
    int s = 0;
    if (i + 3 < N) {
        int4 v = *(const int4*)(counts + i);
        s = v.x + v.y + v.z + v.w;
    } else {
        for (int q = 0; q < 4; ++q) if (i + q < N) s += counts[i + q];
    }
    #pragma unroll
    for (int off = 32; off >= 1; off >>= 1) s += __shfl_down(s, off, 64);
    __shared__ int ws[4];
    if ((tid & 63) == 0) ws[tid >> 6] = s;
    __syncthreads();
    if (tid == 0) btot[blockIdx.x] = ws[0] + ws[1] + ws[2] + ws[3];
}

// pass2: exclusive scan of nb (<=1024) block totals, single block
__global__ __launch_bounds__(1024) void scan_pass2(
    const int* __restrict__ btot, int* __restrict__ boff, int nb)
{
    __shared__ int wsum[16];
    int tid = threadIdx.x, lane = tid & 63, wid = tid >> 6;
    int x = (tid < nb) ? btot[tid] : 0;
    int v = x;
    #pragma unroll
    for (int off = 1; off < 64; off <<= 1) {
        int y = __shfl_up(v, off, 64);
        if (lane >= off) v += y;
    }
    if (lane == 63) wsum[wid] = v;
    __syncthreads();
    if (wid == 0 && lane < 16) {
        int s = wsum[lane];
        #pragma unroll
        for (int off = 1; off < 16; off <<= 1) {
            int y = __shfl_up(s, off, 64);
            if (lane >= off) s += y;
        }
        wsum[lane] = s;
    }
    __syncthreads();
    int wexcl = wid ? wsum[wid - 1] : 0;
    if (tid < nb) boff[tid] = wexcl + v - x;
}

// pass3: per-chunk exclusive scan + block offset -> row_start (in place) & cursor
__global__ __launch_bounds__(256) void scan_pass3(
    int* __restrict__ row_start, int* __restrict__ cursor,
    const int* __restrict__ boff, int N, int E)
{
    int tid = threadIdx.x;
    int base = blockIdx.x * 1024 + tid * 4;
    int c0 = 0, c1 = 0, c2 = 0, c3 = 0;
    if (base + 3 < N) {
        int4 v = *(const int4*)(row_start + base);
        c0 = v.x; c1 = v.y; c2 = v.z; c3 = v.w;
    } else {
        if (base + 0 < N) c0 = row_start[base + 0];
        if (base + 1 < N) c1 = row_start[base + 1];
        if (base + 2 < N) c2 = row_start[base + 2];
        if (base + 3 < N) c3 = row_start[base + 3];
    }
    int s0 = c0, s1 = s0 + c1, s2 = s1 + c2, s3 = s2 + c3;
    int lane = tid & 63, wid = tid >> 6;
    int v = s3;
    #pragma unroll
    for (int off = 1; off < 64; off <<= 1) {
        int y = __shfl_up(v, off, 64);
        if (lane >= off) v += y;
    }
    __shared__ int ws[4];
    if (lane == 63) ws[wid] = v;
    __syncthreads();
    int wexcl = 0;
    for (int q = 0; q < wid; ++q) wexcl += ws[q];
    int texcl = wexcl + (v - s3) + boff[blockIdx.x];
    int e0 = texcl, e1 = texcl + s0, e2 = texcl + s1, e3 = texcl + s2;
    if (base + 0 < N) { row_start[base + 0] = e0; cursor[base + 0] = e0; }
    if (base + 1 < N) { row_start[base + 1] = e1; cursor[base + 1] = e1; }
    if (base + 2 < N) { row_start[base + 2] = e2; cursor[base + 2] = e2; }
    if (base + 3 < N) { row_start[base + 3] = e3; cursor[base + 3] = e3; }
    if (blockIdx.x == 0 && tid == 0) row_start[N] = E;
}

__global__ __launch_bounds__(256) void scatter_sort_kernel(
    const int* __restrict__ rows, const int* __restrict__ cols,
    const float* __restrict__ vals, int* __restrict__ cursor,
    uint2* __restrict__ sedge, int E)
{
    int e = blockIdx.x * 256 + threadIdx.x;
    if (e < E) {
        int r = rows[e];
        int p = atomicAdd(&cursor[r], 1);
        sedge[p] = make_uint2((unsigned)cols[e], __float_as_uint(vals[e]));
    }
}

// One wave per row; 64 lanes x float2 accumulator.
__global__ __launch_bounds__(256) void spmm_kernel(
    const float2* __restrict__ feat2,
    const int* __restrict__ row_start,
    const uint2* __restrict__ sedge,
    float2* __restrict__ h2, int N)
{
    int gw = (blockIdx.x * 256 + threadIdx.x) >> 6;
    int lane = threadIdx.x & 63;
    if (gw >= N) return;

    int s = row_start[gw];
    int e = row_start[gw + 1];

    float2 acc = make_float2(0.f, 0.f);
    int j = s;
    for (; j + 1 < e; j += 2) {
        uint2 e0 = sedge[j], e1 = sedge[j + 1];
        float v0 = __uint_as_float(e0.y), v1 = __uint_as_float(e1.y);
        float2 f0 = feat2[(size_t)e0.x * 64 + lane];
        float2 f1 = feat2[(size_t)e1.x * 64 + lane];
        acc.x = fmaf(v0, f0.x, acc.x);
        acc.y = fmaf(v0, f0.y, acc.y);
        acc.x = fmaf(v1, f1.x, acc.x);
        acc.y = fmaf(v1, f1.y, acc.y);
    }
    if (j < e) {
        uint2 e0 = sedge[j];
        float v = __uint_as_float(e0.y);
        float2 f = feat2[(size_t)e0.x * 64 + lane];
        acc.x = fmaf(v, f.x, acc.x);
        acc.y = fmaf(v, f.y, acc.y);
    }
    h2[(size_t)gw * 64 + lane] = acc;
}

// ===========================================================================
// W -> WT bf16: WT[c][k] = (k<128 ? W1[k][c] : W2[k-128][c]), [128][256]
// ===========================================================================
__global__ __launch_bounds__(256) void wconv_kernel(
    const float* __restrict__ W1, const float* __restrict__ W2,
    unsigned short* __restrict__ WT)
{
    int idx = blockIdx.x * 256 + threadIdx.x;   // 32768
    int c = idx & 127;
    int k = idx >> 7;
    float w = (k < 128) ? W1[k * 128 + c] : W2[(k - 128) * 128 + c];
    WT[c * 256 + k] = f2bf(w);
}

// ===========================================================================
// MFMA fused GEMM: out = leakyrelu([A|M] @ [W1;W2] + b1 + b2)
// 256 thr / 64 nodes; AM staged bf16 in LDS (32KB, XOR-16B swizzled);
// waves 2x2 over (rows 32, cols 64); 2x4 frags of 16x16; K=256 in 8 steps.
// ===========================================================================
__global__ __launch_bounds__(256) void mfma_gemm_kernel(
    const float4* __restrict__ feat4, const float4* __restrict__ h4,
    const unsigned short* __restrict__ WT,
    const float* __restrict__ b1, const float* __restrict__ b2,
    float* __restrict__ out, int N)
{
    __shared__ __align__(16) unsigned char am_raw[64 * 512];  // [node][256 bf16]

    const int tid = threadIdx.x;
    const int block0 = blockIdx.x * BM;

    // --- stage A=(f+h), M=(f*h) as bf16, swizzled ---
    #pragma unroll
    for (int it = 0; it < 8; ++it) {
        int idx  = tid + it * 256;        // 2048 = 64 nodes x 32 float4s
        int node = idx >> 5;
        int p    = idx & 31;
        int g    = block0 + node;
        float4 fv = make_float4(0.f, 0.f, 0.f, 0.f);
        float4 hv = make_float4(0.f, 0.f, 0.f, 0.f);
        if (g < N) { fv = feat4[g * 32 + p]; hv = h4[g * 32 + p]; }
        ushort4 av = make_ushort4(f2bf(fv.x + hv.x), f2bf(fv.y + hv.y),
                                  f2bf(fv.z + hv.z), f2bf(fv.w + hv.w));
        ushort4 mv = make_ushort4(f2bf(fv.x * hv.x), f2bf(fv.y * hv.y),
                                  f2bf(fv.z * hv.z), f2bf(fv.w * hv.w));
        int swz = (node & 7) << 4;
        *(ushort4*)(am_raw + node * 512 + ((p * 8) ^ swz))       = av;
        *(ushort4*)(am_raw + node * 512 + ((256 + p * 8) ^ swz)) = mv;
    }
    __syncthreads();

    const int lane = tid & 63;
    const int w    = tid >> 6;
    const int wr   = w >> 1;          // 0..1 row-block of 32
    const int wc   = w & 1;           // 0..1 col-block of 64
    const int l15  = lane & 15;
    const int lk   = lane >> 4;       // 0..3
    const int rswz = (l15 & 7) << 4;  // row&7 == l15&7 for both row-frags

    f32x4 acc[2][4] = {};

    const char* WTc = (const char*)WT;
    const unsigned char* arow0 = am_raw + (wr * 32 + l15) * 512;
    const unsigned char* arow1 = arow0 + 16 * 512;

    #pragma unroll
    for (int ks = 0; ks < 8; ++ks) {
        int kbyte = ks * 64 + lk * 16;
        int akoff = kbyte ^ rswz;
        short8 a0 = *(const short8*)(arow0 + akoff);
        short8 a1 = *(const short8*)(arow1 + akoff);
        short8 b[4];
        #pragma unroll
        for (int nc = 0; nc < 4; ++nc) {
            int col = wc * 64 + nc * 16 + l15;
            b[nc] = *(const short8*)(WTc + col * 512 + kbyte);
        }
        #pragma unroll
        for (int nc = 0; nc < 4; ++nc) {
            acc[0][nc] = __builtin_amdgcn_mfma_f32_16x16x32_bf16(a0, b[nc], acc[0][nc], 0, 0, 0);
            acc[1][nc] = __builtin_amdgcn_mfma_f32_16x16x32_bf16(a1, b[nc], acc[1][nc], 0, 0, 0);
        }
    }

    // --- epilogue: bias (fp32) + leakyrelu, scalar stores ---
    #pragma unroll
    for (int nc = 0; nc < 4; ++nc) {
        int col = wc * 64 + nc * 16 + l15;
        float bias = b1[col] + b2[col];
        #pragma unroll
        for (int mr = 0; mr < 2; ++mr) {
            int rbase = block0 + wr * 32 + mr * 16 + lk * 4;
            #pragma unroll
            for (int r = 0; r < 4; ++r) {
                int row = rbase + r;
                if (row < N) {
                    float v = acc[mr][nc][r] + bias;
                    out[row * 128 + col] = (v >= 0.f) ? v : 0.01f * v;
                }
            }
        }
    }
}

// ===========================================================================
// Fallback path (tiny ws): atomic scatter + fp32 VALU GEMM (round-1 code)
// ===========================================================================
__global__ __launch_bounds__(256) void edge_scatter_kernel(
    const float4* __restrict__ feat4, const int* __restrict__ rows,
    const int* __restrict__ cols, const float* __restrict__ vals,
    float* __restrict__ h, int E)
{
    int idx = blockIdx.x * 256 + threadIdx.x;
    if (idx >= E * 32) return;
    int e = idx >> 5;
    int p = idx & 31;
    int r = rows[e];
    int c = cols[e];
    float v = vals[e];
    float4 f = feat4[c * 32 + p];
    float* hr = h + (long long)r * D + p * 4;
    unsafeAtomicAdd(hr + 0, v * f.x);
    unsafeAtomicAdd(hr + 1, v * f.y);
    unsafeAtomicAdd(hr + 2, v * f.z);
    unsafeAtomicAdd(hr + 3, v * f.w);
}

__global__ __launch_bounds__(256) void fused_gemm_kernel(
    const float* __restrict__ feat, const float* __restrict__ h,
    const float* __restrict__ W1, const float* __restrict__ b1,
    const float* __restrict__ W2, const float* __restrict__ b2,
    float* __restrict__ out, int N)
{
    __shared__ float a_lds[BM][D];
    __shared__ float m_lds[BM][D];
    const int tid = threadIdx.x;
    const int block0 = blockIdx.x * BM;
    const float4* feat4 = (const float4*)feat;
    const float4* h4    = (const float4*)h;
    #pragma unroll
    for (int it = 0; it < 8; ++it) {
        int idx  = tid + it * 256;
        int node = idx >> 5;
        int p    = idx & 31;
        int gnode = block0 + node;
        float4 fv = make_float4(0.f, 0.f, 0.f, 0.f);
        float4 hv = make_float4(0.f, 0.f, 0.f, 0.f);
        if (gnode < N) { fv = feat4[gnode * 32 + p]; hv = h4[gnode * 32 + p]; }
        float4 av = make_float4(fv.x + hv.x, fv.y + hv.y, fv.z + hv.z, fv.w + hv.w);
        float4 mv = make_float4(fv.x * hv.x, fv.y * hv.y, fv.z * hv.z, fv.w * hv.w);
        *(float4*)&a_lds[node][p * 4] = av;
        *(float4*)&m_lds[node][p * 4] = mv;
    }
    __syncthreads();
    const int c = tid & 31;
    const int g = tid >> 5;
    float acc[8][4] = {};
    const float4* W1v = (const float4*)W1;
    const float4* W2v = (const float4*)W2;
    for (int k = 0; k < D; ++k) {
        float4 w1 = W1v[k * 32 + c];
        float4 w2 = W2v[k * 32 + c];
        #pragma unroll
        for (int t = 0; t < 8; ++t) {
            float av = a_lds[g + 8 * t][k];
            float mv = m_lds[g + 8 * t][k];
            acc[t][0] = fmaf(av, w1.x, fmaf(mv, w2.x, acc[t][0]));
            acc[t][1] = fmaf(av, w1.y, fmaf(mv, w2.y, acc[t][1]));
            acc[t][2] = fmaf(av, w1.z, fmaf(mv, w2.z, acc[t][2]));
            acc[t][3] = fmaf(av, w1.w, fmaf(mv, w2.w, acc[t][3]));
        }
    }
    float4 bb1 = ((const float4*)b1)[c];
    float4 bb2 = ((const float4*)b2)[c];
    const float bx = bb1.x + bb2.x, by = bb1.y + bb2.y;
    const float bz = bb1.z + bb2.z, bw = bb1.w + bb2.w;
    #pragma unroll
    for (int t = 0; t < 8; ++t) {
        int gnode = block0 + g + 8 * t;
        if (gnode >= N) continue;
        float4 o;
        o.x = acc[t][0] + bx; o.y = acc[t][1] + by;
        o.z = acc[t][2] + bz; o.w = acc[t][3] + bw;
        o.x = (o.x >= 0.f) ? o.x : 0.01f * o.x;
        o.y = (o.y >= 0.f) ? o.y : 0.01f * o.y;
        o.z = (o.z >= 0.f) ? o.z : 0.01f * o.z;
        o.w = (o.w >= 0.f) ? o.w : 0.01f * o.w;
        ((float4*)out)[gnode * 32 + c] = o;
    }
}

extern "C" void kernel_launch(void* const* d_in, const int* in_sizes, int n_in,
                              void* d_out, int out_size, void* d_ws, size_t ws_size,
                              hipStream_t stream) {
    const float* feat = (const float*)d_in[0];
    const int*   rows = (const int*)d_in[1];
    const int*   cols = (const int*)d_in[2];
    const float* vals = (const float*)d_in[3];
    const float* W1   = (const float*)d_in[4];
    const float* b1   = (const float*)d_in[5];
    const float* W2   = (const float*)d_in[6];
    const float* b2   = (const float*)d_in[7];

    const int N = in_sizes[0] / D;
    const int E = in_sizes[1];
    float* out = (float*)d_out;

    const int NB = (N + 1023) / 1024;   // scan chunks (98)

    // ws layout: h | row_start | cursor | pad | sedge | WT | btot | boff
    size_t off = 0;
    float* h = (float*)d_ws;                          off += (size_t)N * D * 4;
    int* row_start = (int*)((char*)d_ws + off);       off += (size_t)(N + 1) * 4;
    int* cursor    = (int*)((char*)d_ws + off);       off += (size_t)N * 4;
    off = (off + 15) & ~(size_t)15;
    uint2* sedge   = (uint2*)((char*)d_ws + off);     off += (size_t)E * 8;
    off = (off + 15) & ~(size_t)15;
    unsigned short* WT = (unsigned short*)((char*)d_ws + off); off += 128 * 256 * 2;
    int* btot = (int*)((char*)d_ws + off);            off += (size_t)NB * 4;
    int* boff = (int*)((char*)d_ws + off);            off += (size_t)NB * 4;
    size_t need = off;

    if (ws_size >= need && NB <= 1024) {
        hipMemsetAsync(row_start, 0, (size_t)(N + 1) * sizeof(int), stream);
        wconv_kernel<<<128, 256, 0, stream>>>(W1, W2, WT);
        hist_kernel<<<(E + 255) / 256, 256, 0, stream>>>(rows, row_start, E);
        scan_pass1<<<NB, 256, 0, stream>>>(row_start, btot, N);
        scan_pass2<<<1, 1024, 0, stream>>>(btot, boff, NB);
        scan_pass3<<<NB, 256, 0, stream>>>(row_start, cursor, boff, N, E);
        scatter_sort_kernel<<<(E + 255) / 256, 256, 0, stream>>>(
            rows, cols, vals, cursor, sedge, E);
        spmm_kernel<<<(N * 64 + 255) / 256, 256, 0, stream>>>(
            (const float2*)feat, row_start, sedge, (float2*)h, N);
        mfma_gemm_kernel<<<(N + BM - 1) / BM, 256, 0, stream>>>(
            (const float4*)feat, (const float4*)h, WT, b1, b2, out, N);
    } else {
        size_t hbytes = (size_t)N * D * sizeof(float);
        float* hh = (ws_size >= hbytes) ? (float*)d_ws : out;
        hipMemsetAsync(hh, 0, hbytes, stream);
        edge_scatter_kernel<<<((size_t)E * 32 + 255) / 256, 256, 0, stream>>>(
            (const float4*)feat, rows, cols, vals, hh, E);
        fused_gemm_kernel<<<(N + BM - 1) / BM, 256, 0, stream>>>(
            feat, hh, W1, b1, W2, b2, out, N);
    }
}

// Round 4
// 346.505 us; speedup vs baseline: 8.2821x; 1.0787x over previous
//
#include <hip/hip_runtime.h>

#define D 128
#define BM 64

typedef short short8 __attribute__((ext_vector_type(8)));
typedef unsigned short ushort8_t __attribute__((ext_vector_type(8)));
typedef float f32x4 __attribute__((ext_vector_type(4)));

__device__ __forceinline__ unsigned short f2bf(float x) {
    unsigned u = __float_as_uint(x);
    unsigned r = (u + 0x7fffu + ((u >> 16) & 1u)) >> 16;   // RNE
    return (unsigned short)r;
}
__device__ __forceinline__ float bf2f(unsigned short u) {
    return __uint_as_float(((unsigned)u) << 16);
}

// ===========================================================================
// features fp32 -> bf16 (linear layout)
// ===========================================================================
__global__ __launch_bounds__(256) void fconv_kernel(
    const float4* __restrict__ feat4, ushort4* __restrict__ fbf4, int total)
{
    int i = blockIdx.x * 256 + threadIdx.x;
    if (i < total) {
        float4 v = feat4[i];
        fbf4[i] = make_ushort4(f2bf(v.x), f2bf(v.y), f2bf(v.z), f2bf(v.w));
    }
}

// ===========================================================================
// CSR build: hist -> hierarchical scan -> scatter_sort (packed uint2)
// ===========================================================================
__global__ __launch_bounds__(256) void hist_kernel(
    const int* __restrict__ rows, int* __restrict__ counts, int E)
{
    int e = blockIdx.x * 256 + threadIdx.x;
    if (e < E) atomicAdd(&counts[rows[e]], 1);
}

__global__ __launch_bounds__(256) void scan_pass1(
    const int* __restrict__ counts, int* __restrict__ btot, int N)
{
    int tid = threadIdx.x;
    int i = blockIdx.x * 1024 + tid * 4;
    int s = 0;
    if (i + 3 < N) {
        int4 v = *(const int4*)(counts + i);
        s = v.x + v.y + v.z + v.w;
    } else {
        for (int q = 0; q < 4; ++q) if (i + q < N) s += counts[i + q];
    }
    #pragma unroll
    for (int off = 32; off >= 1; off >>= 1) s += __shfl_down(s, off, 64);
    __shared__ int ws[4];
    if ((tid & 63) == 0) ws[tid >> 6] = s;
    __syncthreads();
    if (tid == 0) btot[blockIdx.x] = ws[0] + ws[1] + ws[2] + ws[3];
}

__global__ __launch_bounds__(1024) void scan_pass2(
    const int* __restrict__ btot, int* __restrict__ boff, int nb)
{
    __shared__ int wsum[16];
    int tid = threadIdx.x, lane = tid & 63, wid = tid >> 6;
    int x = (tid < nb) ? btot[tid] : 0;
    int v = x;
    #pragma unroll
    for (int off = 1; off < 64; off <<= 1) {
        int y = __shfl_up(v, off, 64);
        if (lane >= off) v += y;
    }
    if (lane == 63) wsum[wid] = v;
    __syncthreads();
    if (wid == 0 && lane < 16) {
        int s = wsum[lane];
        #pragma unroll
        for (int off = 1; off < 16; off <<= 1) {
            int y = __shfl_up(s, off, 64);
            if (lane >= off) s += y;
        }
        wsum[lane] = s;
    }
    __syncthreads();
    int wexcl = wid ? wsum[wid - 1] : 0;
    if (tid < nb) boff[tid] = wexcl + v - x;
}

__global__ __launch_bounds__(256) void scan_pass3(
    int* __restrict__ row_start, int* __restrict__ cursor,
    const int* __restrict__ boff, int N, int E)
{
    int tid = threadIdx.x;
    int base = blockIdx.x * 1024 + tid * 4;
    int c0 = 0, c1 = 0, c2 = 0, c3 = 0;
    if (base + 3 < N) {
        int4 v = *(const int4*)(row_start + base);
        c0 = v.x; c1 = v.y; c2 = v.z; c3 = v.w;
    } else {
        if (base + 0 < N) c0 = row_start[base + 0];
        if (base + 1 < N) c1 = row_start[base + 1];
        if (base + 2 < N) c2 = row_start[base + 2];
        if (base + 3 < N) c3 = row_start[base + 3];
    }
    int s0 = c0, s1 = s0 + c1, s2 = s1 + c2, s3 = s2 + c3;
    int lane = tid & 63, wid = tid >> 6;
    int v = s3;
    #pragma unroll
    for (int off = 1; off < 64; off <<= 1) {
        int y = __shfl_up(v, off, 64);
        if (lane >= off) v += y;
    }
    __shared__ int ws[4];
    if (lane == 63) ws[wid] = v;
    __syncthreads();
    int wexcl = 0;
    for (int q = 0; q < wid; ++q) wexcl += ws[q];
    int texcl = wexcl + (v - s3) + boff[blockIdx.x];
    int e0 = texcl, e1 = texcl + s0, e2 = texcl + s1, e3 = texcl + s2;
    if (base + 0 < N) { row_start[base + 0] = e0; cursor[base + 0] = e0; }
    if (base + 1 < N) { row_start[base + 1] = e1; cursor[base + 1] = e1; }
    if (base + 2 < N) { row_start[base + 2] = e2; cursor[base + 2] = e2; }
    if (base + 3 < N) { row_start[base + 3] = e3; cursor[base + 3] = e3; }
    if (blockIdx.x == 0 && tid == 0) row_start[N] = E;
}

__global__ __launch_bounds__(256) void scatter_sort_kernel(
    const int* __restrict__ rows, const int* __restrict__ cols,
    const float* __restrict__ vals, int* __restrict__ cursor,
    uint2* __restrict__ sedge, int E)
{
    int e = blockIdx.x * 256 + threadIdx.x;
    if (e < E) {
        int r = rows[e];
        int p = atomicAdd(&cursor[r], 1);
        sedge[p] = make_uint2((unsigned)cols[e], __float_as_uint(vals[e]));
    }
}

// ===========================================================================
// SpMM + A/M build: 4 rows per wave (16 lanes x ushort8 = 16B/lane bf16).
// Gathers bf16 features; keeps h in fp32 regs; loads own fp32 feature row;
// writes a=(f+h), m=(f*h) as bf16 into ambf[row][512B], PRE-SWIZZLED with
// the GEMM's LDS XOR pattern (byteoff ^ ((row&7)<<4)).
// ===========================================================================
__global__ __launch_bounds__(256) void spmm_ab_kernel(
    const float4* __restrict__ feat4,
    const ushort8_t* __restrict__ fbf8,
    const int* __restrict__ row_start,
    const uint2* __restrict__ sedge,
    unsigned char* __restrict__ ambf, int N)
{
    int t = blockIdx.x * 256 + threadIdx.x;
    int row = t >> 4;            // one row per quarter-wave
    int l   = t & 15;            // 16 lanes x 8 bf16 = 128 cols
    if (row >= N) return;

    int s = row_start[row];
    int e = row_start[row + 1];

    float acc[8] = {};
    int j = s;
    for (; j + 1 < e; j += 2) {
        uint2 e0 = sedge[j], e1 = sedge[j + 1];
        float v0 = __uint_as_float(e0.y), v1 = __uint_as_float(e1.y);
        ushort8_t f0 = fbf8[(size_t)e0.x * 16 + l];
        ushort8_t f1 = fbf8[(size_t)e1.x * 16 + l];
        #pragma unroll
        for (int q = 0; q < 8; ++q) {
            acc[q] = fmaf(v0, bf2f(f0[q]), acc[q]);
            acc[q] = fmaf(v1, bf2f(f1[q]), acc[q]);
        }
    }
    if (j < e) {
        uint2 e0 = sedge[j];
        float v = __uint_as_float(e0.y);
        ushort8_t f = fbf8[(size_t)e0.x * 16 + l];
        #pragma unroll
        for (int q = 0; q < 8; ++q) acc[q] = fmaf(v, bf2f(f[q]), acc[q]);
    }

    // own feature row (fp32 for accuracy), 8 floats = 2 float4
    float4 fa = feat4[(size_t)row * 32 + 2 * l];
    float4 fb = feat4[(size_t)row * 32 + 2 * l + 1];
    float f[8] = { fa.x, fa.y, fa.z, fa.w, fb.x, fb.y, fb.z, fb.w };

    ushort8_t av, mv;
    #pragma unroll
    for (int q = 0; q < 8; ++q) {
        av[q] = f2bf(f[q] + acc[q]);
        mv[q] = f2bf(f[q] * acc[q]);
    }

    int swz = (row & 7) << 4;
    unsigned char* rowp = ambf + (size_t)row * 512;
    *(ushort8_t*)(rowp + ((16 * l) ^ swz))       = av;
    *(ushort8_t*)(rowp + 256 + ((16 * l) ^ swz)) = mv;
}

// ===========================================================================
// W -> WT bf16: WT[c][k] = (k<128 ? W1[k][c] : W2[k-128][c]), [128][256]
// ===========================================================================
__global__ __launch_bounds__(256) void wconv_kernel(
    const float* __restrict__ W1, const float* __restrict__ W2,
    unsigned short* __restrict__ WT)
{
    int idx = blockIdx.x * 256 + threadIdx.x;   // 32768
    int c = idx & 127;
    int k = idx >> 7;
    float w = (k < 128) ? W1[k * 128 + c] : W2[(k - 128) * 128 + c];
    WT[c * 256 + k] = f2bf(w);
}

// ===========================================================================
// MFMA fused GEMM v2: stage = pure 32KB copy of pre-swizzled ambf tile.
// waves 2x2 over (rows 32, cols 64); 2x4 frags of 16x16x32 bf16; K=256.
// ===========================================================================
__global__ __launch_bounds__(256) void mfma_gemm2_kernel(
    const unsigned char* __restrict__ ambf,
    const unsigned short* __restrict__ WT,
    const float* __restrict__ b1, const float* __restrict__ b2,
    float* __restrict__ out, int N)
{
    __shared__ __align__(16) unsigned char am_raw[64 * 512];

    const int tid = threadIdx.x;
    const int block0 = blockIdx.x * BM;

    // --- stage: linear copy (swizzle already baked into global data) ---
    const short8* src = (const short8*)(ambf + (size_t)block0 * 512);
    short8* dst = (short8*)am_raw;
    #pragma unroll
    for (int it = 0; it < 8; ++it) {
        int idx = tid + it * 256;     // 2048 x 16B = 32KB
        dst[idx] = src[idx];
    }
    __syncthreads();

    const int lane = tid & 63;
    const int w    = tid >> 6;
    const int wr   = w >> 1;
    const int wc   = w & 1;
    const int l15  = lane & 15;
    const int lk   = lane >> 4;
    const int rswz = (l15 & 7) << 4;

    f32x4 acc[2][4] = {};

    const char* WTc = (const char*)WT;
    const unsigned char* arow0 = am_raw + (wr * 32 + l15) * 512;
    const unsigned char* arow1 = arow0 + 16 * 512;

    #pragma unroll
    for (int ks = 0; ks < 8; ++ks) {
        int kbyte = ks * 64 + lk * 16;
        int akoff = kbyte ^ rswz;
        short8 a0 = *(const short8*)(arow0 + akoff);
        short8 a1 = *(const short8*)(arow1 + akoff);
        short8 b[4];
        #pragma unroll
        for (int nc = 0; nc < 4; ++nc) {
            int col = wc * 64 + nc * 16 + l15;
            b[nc] = *(const short8*)(WTc + col * 512 + kbyte);
        }
        #pragma unroll
        for (int nc = 0; nc < 4; ++nc) {
            acc[0][nc] = __builtin_amdgcn_mfma_f32_16x16x32_bf16(a0, b[nc], acc[0][nc], 0, 0, 0);
            acc[1][nc] = __builtin_amdgcn_mfma_f32_16x16x32_bf16(a1, b[nc], acc[1][nc], 0, 0, 0);
        }
    }

    #pragma unroll
    for (int nc = 0; nc < 4; ++nc) {
        int col = wc * 64 + nc * 16 + l15;
        float bias = b1[col] + b2[col];
        #pragma unroll
        for (int mr = 0; mr < 2; ++mr) {
            int rbase = block0 + wr * 32 + mr * 16 + lk * 4;
            #pragma unroll
            for (int r = 0; r < 4; ++r) {
                int row = rbase + r;
                if (row < N) {
                    float v = acc[mr][nc][r] + bias;
                    out[row * 128 + col] = (v >= 0.f) ? v : 0.01f * v;
                }
            }
        }
    }
}

// ===========================================================================
// Tier-2 fallback: round-3 spmm (fp32) + gemm (f2bf staging)
// ===========================================================================
__global__ __launch_bounds__(256) void spmm_kernel(
    const float2* __restrict__ feat2,
    const int* __restrict__ row_start,
    const uint2* __restrict__ sedge,
    float2* __restrict__ h2, int N)
{
    int gw = (blockIdx.x * 256 + threadIdx.x) >> 6;
    int lane = threadIdx.x & 63;
    if (gw >= N) return;
    int s = row_start[gw];
    int e = row_start[gw + 1];
    float2 acc = make_float2(0.f, 0.f);
    int j = s;
    for (; j + 1 < e; j += 2) {
        uint2 e0 = sedge[j], e1 = sedge[j + 1];
        float v0 = __uint_as_float(e0.y), v1 = __uint_as_float(e1.y);
        float2 f0 = feat2[(size_t)e0.x * 64 + lane];
        float2 f1 = feat2[(size_t)e1.x * 64 + lane];
        acc.x = fmaf(v0, f0.x, acc.x);
        acc.y = fmaf(v0, f0.y, acc.y);
        acc.x = fmaf(v1, f1.x, acc.x);
        acc.y = fmaf(v1, f1.y, acc.y);
    }
    if (j < e) {
        uint2 e0 = sedge[j];
        float v = __uint_as_float(e0.y);
        float2 f = feat2[(size_t)e0.x * 64 + lane];
        acc.x = fmaf(v, f.x, acc.x);
        acc.y = fmaf(v, f.y, acc.y);
    }
    h2[(size_t)gw * 64 + lane] = acc;
}

__global__ __launch_bounds__(256) void mfma_gemm_kernel(
    const float4* __restrict__ feat4, const float4* __restrict__ h4,
    const unsigned short* __restrict__ WT,
    const float* __restrict__ b1, const float* __restrict__ b2,
    float* __restrict__ out, int N)
{
    __shared__ __align__(16) unsigned char am_raw[64 * 512];
    const int tid = threadIdx.x;
    const int block0 = blockIdx.x * BM;
    #pragma unroll
    for (int it = 0; it < 8; ++it) {
        int idx  = tid + it * 256;
        int node = idx >> 5;
        int p    = idx & 31;
        int g    = block0 + node;
        float4 fv = make_float4(0.f, 0.f, 0.f, 0.f);
        float4 hv = make_float4(0.f, 0.f, 0.f, 0.f);
        if (g < N) { fv = feat4[g * 32 + p]; hv = h4[g * 32 + p]; }
        ushort4 av = make_ushort4(f2bf(fv.x + hv.x), f2bf(fv.y + hv.y),
                                  f2bf(fv.z + hv.z), f2bf(fv.w + hv.w));
        ushort4 mv = make_ushort4(f2bf(fv.x * hv.x), f2bf(fv.y * hv.y),
                                  f2bf(fv.z * hv.z), f2bf(fv.w * hv.w));
        int swz = (node & 7) << 4;
        *(ushort4*)(am_raw + node * 512 + ((p * 8) ^ swz))       = av;
        *(ushort4*)(am_raw + node * 512 + ((256 + p * 8) ^ swz)) = mv;
    }
    __syncthreads();
    const int lane = tid & 63;
    const int w    = tid >> 6;
    const int wr   = w >> 1;
    const int wc   = w & 1;
    const int l15  = lane & 15;
    const int lk   = lane >> 4;
    const int rswz = (l15 & 7) << 4;
    f32x4 acc[2][4] = {};
    const char* WTc = (const char*)WT;
    const unsigned char* arow0 = am_raw + (wr * 32 + l15) * 512;
    const unsigned char* arow1 = arow0 + 16 * 512;
    #pragma unroll
    for (int ks = 0; ks < 8; ++ks) {
        int kbyte = ks * 64 + lk * 16;
        int akoff = kbyte ^ rswz;
        short8 a0 = *(const short8*)(arow0 + akoff);
        short8 a1 = *(const short8*)(arow1 + akoff);
        short8 b[4];
        #pragma unroll
        for (int nc = 0; nc < 4; ++nc) {
            int col = wc * 64 + nc * 16 + l15;
            b[nc] = *(const short8*)(WTc + col * 512 + kbyte);
        }
        #pragma unroll
        for (int nc = 0; nc < 4; ++nc) {
            acc[0][nc] = __builtin_amdgcn_mfma_f32_16x16x32_bf16(a0, b[nc], acc[0][nc], 0, 0, 0);
            acc[1][nc] = __builtin_amdgcn_mfma_f32_16x16x32_bf16(a1, b[nc], acc[1][nc], 0, 0, 0);
        }
    }
    #pragma unroll
    for (int nc = 0; nc < 4; ++nc) {
        int col = wc * 64 + nc * 16 + l15;
        float bias = b1[col] + b2[col];
        #pragma unroll
        for (int mr = 0; mr < 2; ++mr) {
            int rbase = block0 + wr * 32 + mr * 16 + lk * 4;
            #pragma unroll
            for (int r = 0; r < 4; ++r) {
                int row = rbase + r;
                if (row < N) {
                    float v = acc[mr][nc][r] + bias;
                    out[row * 128 + col] = (v >= 0.f) ? v : 0.01f * v;
                }
            }
        }
    }
}

// ===========================================================================
// Tier-3 fallback: atomic scatter + fp32 VALU GEMM
// ===========================================================================
__global__ __launch_bounds__(256) void edge_scatter_kernel(
    const float4* __restrict__ feat4, const int* __restrict__ rows,
    const int* __restrict__ cols, const float* __restrict__ vals,
    float* __restrict__ h, int E)
{
    int idx = blockIdx.x * 256 + threadIdx.x;
    if (idx >= E * 32) return;
    int e = idx >> 5;
    int p = idx & 31;
    int r = rows[e];
    int c = cols[e];
    float v = vals[e];
    float4 f = feat4[c * 32 + p];
    float* hr = h + (long long)r * D + p * 4;
    unsafeAtomicAdd(hr + 0, v * f.x);
    unsafeAtomicAdd(hr + 1, v * f.y);
    unsafeAtomicAdd(hr + 2, v * f.z);
    unsafeAtomicAdd(hr + 3, v * f.w);
}

__global__ __launch_bounds__(256) void fused_gemm_kernel(
    const float* __restrict__ feat, const float* __restrict__ h,
    const float* __restrict__ W1, const float* __restrict__ b1,
    const float* __restrict__ W2, const float* __restrict__ b2,
    float* __restrict__ out, int N)
{
    __shared__ float a_lds[BM][D];
    __shared__ float m_lds[BM][D];
    const int tid = threadIdx.x;
    const int block0 = blockIdx.x * BM;
    const float4* feat4 = (const float4*)feat;
    const float4* h4    = (const float4*)h;
    #pragma unroll
    for (int it = 0; it < 8; ++it) {
        int idx  = tid + it * 256;
        int node = idx >> 5;
        int p    = idx & 31;
        int gnode = block0 + node;
        float4 fv = make_float4(0.f, 0.f, 0.f, 0.f);
        float4 hv = make_float4(0.f, 0.f, 0.f, 0.f);
        if (gnode < N) { fv = feat4[gnode * 32 + p]; hv = h4[gnode * 32 + p]; }
        float4 av = make_float4(fv.x + hv.x, fv.y + hv.y, fv.z + hv.z, fv.w + hv.w);
        float4 mv = make_float4(fv.x * hv.x, fv.y * hv.y, fv.z * hv.z, fv.w * hv.w);
        *(float4*)&a_lds[node][p * 4] = av;
        *(float4*)&m_lds[node][p * 4] = mv;
    }
    __syncthreads();
    const int c = tid & 31;
    const int g = tid >> 5;
    float acc[8][4] = {};
    const float4* W1v = (const float4*)W1;
    const float4* W2v = (const float4*)W2;
    for (int k = 0; k < D; ++k) {
        float4 w1 = W1v[k * 32 + c];
        float4 w2 = W2v[k * 32 + c];
        #pragma unroll
        for (int t = 0; t < 8; ++t) {
            float av = a_lds[g + 8 * t][k];
            float mv = m_lds[g + 8 * t][k];
            acc[t][0] = fmaf(av, w1.x, fmaf(mv, w2.x, acc[t][0]));
            acc[t][1] = fmaf(av, w1.y, fmaf(mv, w2.y, acc[t][1]));
            acc[t][2] = fmaf(av, w1.z, fmaf(mv, w2.z, acc[t][2]));
            acc[t][3] = fmaf(av, w1.w, fmaf(mv, w2.w, acc[t][3]));
        }
    }
    float4 bb1 = ((const float4*)b1)[c];
    float4 bb2 = ((const float4*)b2)[c];
    const float bx = bb1.x + bb2.x, by = bb1.y + bb2.y;
    const float bz = bb1.z + bb2.z, bw = bb1.w + bb2.w;
    #pragma unroll
    for (int t = 0; t < 8; ++t) {
        int gnode = block0 + g + 8 * t;
        if (gnode >= N) continue;
        float4 o;
        o.x = acc[t][0] + bx; o.y = acc[t][1] + by;
        o.z = acc[t][2] + bz; o.w = acc[t][3] + bw;
        o.x = (o.x >= 0.f) ? o.x : 0.01f * o.x;
        o.y = (o.y >= 0.f) ? o.y : 0.01f * o.y;
        o.z = (o.z >= 0.f) ? o.z : 0.01f * o.z;
        o.w = (o.w >= 0.f) ? o.w : 0.01f * o.w;
        ((float4*)out)[gnode * 32 + c] = o;
    }
}

extern "C" void kernel_launch(void* const* d_in, const int* in_sizes, int n_in,
                              void* d_out, int out_size, void* d_ws, size_t ws_size,
                              hipStream_t stream) {
    const float* feat = (const float*)d_in[0];
    const int*   rows = (const int*)d_in[1];
    const int*   cols = (const int*)d_in[2];
    const float* vals = (const float*)d_in[3];
    const float* W1   = (const float*)d_in[4];
    const float* b1   = (const float*)d_in[5];
    const float* W2   = (const float*)d_in[6];
    const float* b2   = (const float*)d_in[7];

    const int N = in_sizes[0] / D;
    const int E = in_sizes[1];
    float* out = (float*)d_out;
    const int NB = (N + 1023) / 1024;

    // --- Tier-1 ws layout: ambf | row_start | cursor | sedge | WT | featbf | btot | boff
    size_t off = 0;
    unsigned char* ambf = (unsigned char*)d_ws;        off += (size_t)N * 512;
    int* row_start = (int*)((char*)d_ws + off);        off += (size_t)(N + 1) * 4;
    int* cursor    = (int*)((char*)d_ws + off);        off += (size_t)N * 4;
    off = (off + 15) & ~(size_t)15;
    uint2* sedge   = (uint2*)((char*)d_ws + off);      off += (size_t)E * 8;
    off = (off + 15) & ~(size_t)15;
    unsigned short* WT = (unsigned short*)((char*)d_ws + off); off += 128 * 256 * 2;
    unsigned short* featbf = (unsigned short*)((char*)d_ws + off); off += (size_t)N * D * 2;
    int* btot = (int*)((char*)d_ws + off);             off += (size_t)NB * 4;
    int* boff = (int*)((char*)d_ws + off);             off += (size_t)NB * 4;
    size_t need1 = off;

    if (ws_size >= need1 && NB <= 1024) {
        hipMemsetAsync(row_start, 0, (size_t)(N + 1) * sizeof(int), stream);
        fconv_kernel<<<(N * 32 + 255) / 256, 256, 0, stream>>>(
            (const float4*)feat, (ushort4*)featbf, N * 32);
        wconv_kernel<<<128, 256, 0, stream>>>(W1, W2, WT);
        hist_kernel<<<(E + 255) / 256, 256, 0, stream>>>(rows, row_start, E);
        scan_pass1<<<NB, 256, 0, stream>>>(row_start, btot, N);
        scan_pass2<<<1, 1024, 0, stream>>>(btot, boff, NB);
        scan_pass3<<<NB, 256, 0, stream>>>(row_start, cursor, boff, N, E);
        scatter_sort_kernel<<<(E + 255) / 256, 256, 0, stream>>>(
            rows, cols, vals, cursor, sedge, E);
        spmm_ab_kernel<<<(N * 16 + 255) / 256, 256, 0, stream>>>(
            (const float4*)feat, (const ushort8_t*)featbf, row_start, sedge,
            ambf, N);
        mfma_gemm2_kernel<<<(N + BM - 1) / BM, 256, 0, stream>>>(
            ambf, WT, b1, b2, out, N);
        return;
    }

    // --- Tier-2 ws layout: h | row_start | cursor | sedge | WT | btot | boff
    off = 0;
    float* h = (float*)d_ws;                           off += (size_t)N * D * 4;
    row_start = (int*)((char*)d_ws + off);             off += (size_t)(N + 1) * 4;
    cursor    = (int*)((char*)d_ws + off);             off += (size_t)N * 4;
    off = (off + 15) & ~(size_t)15;
    sedge     = (uint2*)((char*)d_ws + off);           off += (size_t)E * 8;
    off = (off + 15) & ~(size_t)15;
    WT = (unsigned short*)((char*)d_ws + off);         off += 128 * 256 * 2;
    btot = (int*)((char*)d_ws + off);                  off += (size_t)NB * 4;
    boff = (int*)((char*)d_ws + off);                  off += (size_t)NB * 4;
    size_t need2 = off;

    if (ws_size >= need2 && NB <= 1024) {
        hipMemsetAsync(row_start, 0, (size_t)(N + 1) * sizeof(int), stream);
        wconv_kernel<<<128, 256, 0, stream>>>(W1, W2, WT);
        hist_kernel<<<(E + 255) / 256, 256, 0, stream>>>(rows, row_start, E);
        scan_pass1<<<NB, 256, 0, stream>>>(row_start, btot, N);
        scan_pass2<<<1, 1024, 0, stream>>>(btot, boff, NB);
        scan_pass3<<<NB, 256, 0, stream>>>(row_start, cursor, boff, N, E);
        scatter_sort_kernel<<<(E + 255) / 256, 256, 0, stream>>>(
            rows, cols, vals, cursor, sedge, E);
        spmm_kernel<<<(N * 64 + 255) / 256, 256, 0, stream>>>(
            (const float2*)feat, row_start, sedge, (float2*)h, N);
        mfma_gemm_kernel<<<(N + BM - 1) / BM, 256, 0, stream>>>(
            (const float4*)feat, (const float4*)h, WT, b1, b2, out, N);
        return;
    }

    // --- Tier-3: atomic scatter + VALU GEMM
    size_t hbytes = (size_t)N * D * sizeof(float);
    float* hh = (ws_size >= hbytes) ? (float*)d_ws : out;
    hipMemsetAsync(hh, 0, hbytes, stream);
    edge_scatter_kernel<<<((size_t)E * 32 + 255) / 256, 256, 0, stream>>>(
        (const float4*)feat, rows, cols, vals, hh, E);
    fused_gemm_kernel<<<(N + BM - 1) / BM, 256, 0, stream>>>(
        feat, hh, W1, b1, W2, b2, out, N);
}